// Round 5
// baseline (235.825 us; speedup 1.0000x reference)
//
#include <hip/hip_runtime.h>

#define N_NODES 100000
#define N_EDGES 1600000
#define D_IN 128
#define D_HID 128
#define D_LAT 64

#define BSHIFT 8                          // 256 nodes per bucket
#define NB 392                            // ceil(100352 / 256) buckets
#define CAP 4608                          // slots per bucket region (mean 4082 + 8.2 sigma)
#define EPB 4096                          // edges per partition block
#define PART_BLOCKS ((N_EDGES + EPB - 1) / EPB)   // 391
#define CVT_BLOCKS (((long)N_NODES * 128 / 16 + 255) / 256)   // 3125

typedef unsigned short ushort_t;
typedef unsigned int uint_t;
typedef unsigned char uchar_t;
using bf16x8 = __attribute__((ext_vector_type(8))) short;
using f32x4  = __attribute__((ext_vector_type(4))) float;
using f32x2  = __attribute__((ext_vector_type(2))) float;

__device__ inline ushort_t f2bf(float f) {
    uint_t u = __float_as_uint(f);
    return (ushort_t)((u + 0x7fffu + ((u >> 16) & 1u)) >> 16);   // RNE
}
__device__ inline uint_t pack2bf(float a, float b) {
    return (uint_t)f2bf(a) | ((uint_t)f2bf(b) << 16);
}
__device__ inline float bf2f(ushort_t u) {
    return __uint_as_float(((uint_t)u) << 16);
}

// ---------------- fp8 e4m3 helpers (word-select must be compile-time) ----------------
#if __has_builtin(__builtin_amdgcn_cvt_pk_f32_fp8) && __has_builtin(__builtin_amdgcn_cvt_pk_fp8_f32)
#define HW_FP8 1
template<bool HI>
__device__ inline f32x2 fp8pk2f(uint_t v) {
    return __builtin_amdgcn_cvt_pk_f32_fp8(v, HI);       // HI is an ICE here
}
__device__ inline uint_t f2fp8pk4(float a, float b, float c, float d) {
    uint_t w = __builtin_amdgcn_cvt_pk_fp8_f32(a, b, 0, false);
    w = __builtin_amdgcn_cvt_pk_fp8_f32(c, d, w, true);
    return w;
}
__device__ inline uchar_t f2fp8_byte(float f) {
    return (uchar_t)(__builtin_amdgcn_cvt_pk_fp8_f32(f, f, 0, false) & 0xff);
}
#else
// fallback: software e4m3fn (normals exact w/ RNE; subnormals flushed)
__device__ inline float fp8b2f(uint_t b) {
    uint_t em = b & 0x7f;
    if (em == 0) return 0.f;
    uint_t bits = ((em << 20) + (120u << 23)) | ((b & 0x80u) << 24);
    return __uint_as_float(bits);
}
template<bool HI>
__device__ inline f32x2 fp8pk2f(uint_t v) {
    uint_t w = HI ? (v >> 16) : v;
    f32x2 r; r.x = fp8b2f(w & 0xff); r.y = fp8b2f((w >> 8) & 0xff);
    return r;
}
__device__ inline uint_t f2fp8_1(float f) {
    uint_t u = __float_as_uint(f);
    uint_t s = (u >> 31) << 7;
    uint_t au = u & 0x7fffffff;
    if (au >= 0x43e00000u) return s | 0x7e;              // clamp to 448
    if (au < 0x3c000000u) return s;                      // < 2^-7 -> 0 (approx)
    uint_t r = au + 0x0007ffffu + ((au >> 20) & 1u);     // RNE at 3 mantissa bits
    return s | (((r >> 20) - (120u << 3)) & 0x7f);
}
__device__ inline uint_t f2fp8pk4(float a, float b, float c, float d) {
    return f2fp8_1(a) | (f2fp8_1(b) << 8) | (f2fp8_1(c) << 16) | (f2fp8_1(d) << 24);
}
__device__ inline uchar_t f2fp8_byte(float f) { return (uchar_t)f2fp8_1(f); }
#endif

// packed f32x2 accumulate: hipcc emits v_pk_add_f32 (halves the add count);
// per-element accumulation order identical to scalar form.
__device__ inline void accf8x4p(f32x2* a, uint_t w, int b2) {
    a[b2]     += fp8pk2f<false>(w);
    a[b2 + 1] += fp8pk2f<true>(w);
}
__device__ inline void accf8x16p(f32x2* a, uint4 u) {
    accf8x4p(a, u.x, 0); accf8x4p(a, u.y, 2); accf8x4p(a, u.z, 4); accf8x4p(a, u.w, 6);
}

// ---------------- software-pipelined fp8 gather-accumulate ----------------
// RSHIFT = log2(row stride bytes); NV = uint4 chunks per row-slice per lane;
// DEPTH = edges in flight; STRIDE = index stride (2 = edge-parity split).
// Prefetches next batch's csr indices during the current batch's unpack VALU.
template<int RSHIFT, int NV, int DEPTH, int STRIDE = 1>
__device__ inline void gather_acc_fp8n(const uchar_t* __restrict__ base,
                                       const int* __restrict__ idxp,
                                       int n, f32x2* acc) {
    int k = 0;
    int idx[DEPTH];
    if (n >= DEPTH) {
        #pragma unroll
        for (int j = 0; j < DEPTH; ++j) idx[j] = idxp[j * STRIDE];
    }
    while (k + DEPTH <= n) {
        uint4 u[DEPTH][NV];
        #pragma unroll
        for (int j = 0; j < DEPTH; ++j) {
            #pragma unroll
            for (int v = 0; v < NV; ++v)
                u[j][v] = *(const uint4*)(base + ((long)idx[j] << RSHIFT) + v * 16);
        }
        int kn = k + DEPTH;
        if (kn + DEPTH <= n) {
            #pragma unroll
            for (int j = 0; j < DEPTH; ++j) idx[j] = idxp[(kn + j) * STRIDE];
        }
        #pragma unroll
        for (int j = 0; j < DEPTH; ++j) {
            #pragma unroll
            for (int v = 0; v < NV; ++v)
                accf8x16p(acc + v * 8, u[j][v]);
        }
        k = kn;
    }
    if (k < n) {                           // masked DEPTH-wide tail (indices clamped)
        int m = n - k;
        int idr[DEPTH];
        #pragma unroll
        for (int j = 0; j < DEPTH; ++j) {
            int kk = k + j; if (kk > n - 1) kk = n - 1;
            idr[j] = idxp[kk * STRIDE];
        }
        uint4 u[DEPTH][NV];
        #pragma unroll
        for (int j = 0; j < DEPTH; ++j) {
            #pragma unroll
            for (int v = 0; v < NV; ++v)
                u[j][v] = *(const uint4*)(base + ((long)idr[j] << RSHIFT) + v * 16);
        }
        #pragma unroll
        for (int j = 0; j < DEPTH; ++j) {
            if (j < m) {
                #pragma unroll
                for (int v = 0; v < NV; ++v)
                    accf8x16p(acc + v * 8, u[j][v]);
            }
        }
    }
}

// ---------------- fused prep: weight packs + cursor init + x conversion ----------------
// blocks 0..15: pack1; 16..19: pack2l; 20..23: pack2r; 24..25: gCur; 26..: cvt x
__device__ inline void pack_w256(const float* Wl, const float* Wr, ushort_t* pack,
                                 int N, int tid) {
    int lane = tid & 63;
    int t = tid >> 6;
    int kt = t & 7;
    int nt = t >> 3;
    int n = nt * 16 + (lane & 15);
    int kbase = kt * 32 + (lane >> 4) * 8;
    ushort_t v[8];
    #pragma unroll
    for (int j = 0; j < 8; ++j) {
        int k = kbase + j;
        float w = (k < 128) ? Wl[k * N + n] : Wr[(k - 128) * N + n];
        v[j] = f2bf(w);
    }
    *(uint4*)(pack + (long)tid * 8) = *(uint4*)v;
}
__device__ inline void pack_w128(const float* W, ushort_t* pack, int N, int tid) {
    int lane = tid & 63;
    int t = tid >> 6;
    int kt = t & 3;
    int nt = t >> 2;
    int n = nt * 16 + (lane & 15);
    int kbase = kt * 32 + (lane >> 4) * 8;
    ushort_t v[8];
    #pragma unroll
    for (int j = 0; j < 8; ++j) v[j] = f2bf(W[(kbase + j) * N + n]);
    *(uint4*)(pack + (long)tid * 8) = *(uint4*)v;
}

__global__ __launch_bounds__(256) void prep_kernel(
        const float* __restrict__ W1_l, const float* __restrict__ W1_r,
        ushort_t* __restrict__ pack1,
        const float* __restrict__ W2_l, ushort_t* __restrict__ pack2l,
        const float* __restrict__ W2_r, ushort_t* __restrict__ pack2r,
        int* __restrict__ gCur,
        const float* __restrict__ x, ushort_t* __restrict__ xb,
        uchar_t* __restrict__ x8) {
    int b = blockIdx.x;
    if (b < 16) {
        pack_w256(W1_l, W1_r, pack1, 128, b * 256 + threadIdx.x);
    } else if (b < 20) {
        pack_w128(W2_l, pack2l, 64, (b - 16) * 256 + threadIdx.x);
    } else if (b < 24) {
        pack_w128(W2_r, pack2r, 64, (b - 20) * 256 + threadIdx.x);
    } else if (b < 26) {
        int t = (b - 24) * 256 + threadIdx.x;
        if (t < NB) gCur[t] = t * CAP;
    } else {
        long i = ((long)(b - 26) * 256 + threadIdx.x) * 16;
        if (i >= (long)N_NODES * 128) return;
        float4 a = *(const float4*)(x + i);
        float4 bb = *(const float4*)(x + i + 4);
        float4 c = *(const float4*)(x + i + 8);
        float4 d = *(const float4*)(x + i + 12);
        uint4 ob0, ob1;
        ob0.x = pack2bf(a.x, a.y);  ob0.y = pack2bf(a.z, a.w);
        ob0.z = pack2bf(bb.x, bb.y); ob0.w = pack2bf(bb.z, bb.w);
        ob1.x = pack2bf(c.x, c.y);  ob1.y = pack2bf(c.z, c.w);
        ob1.z = pack2bf(d.x, d.y);  ob1.w = pack2bf(d.z, d.w);
        *(uint4*)(xb + i) = ob0;
        *(uint4*)(xb + i + 8) = ob1;
        uint4 o8;
        o8.x = f2fp8pk4(a.x, a.y, a.z, a.w);
        o8.y = f2fp8pk4(bb.x, bb.y, bb.z, bb.w);
        o8.z = f2fp8pk4(c.x, c.y, c.z, c.w);
        o8.w = f2fp8pk4(d.x, d.y, d.z, d.w);
        *(uint4*)(x8 + i) = o8;
    }
}

// ---------------- CSR build: fixed-stride bucketed counting sort ----------------
__global__ __launch_bounds__(256) void bucket_scatter_kernel(const int* __restrict__ src,
                                                             const int* __restrict__ dst,
                                                             int* __restrict__ gCur,
                                                             int* __restrict__ bedges) {
    __shared__ int h[NB];
    __shared__ int start[NB];
    for (int j = threadIdx.x; j < NB; j += 256) h[j] = 0;
    __syncthreads();
    long base = (long)blockIdx.x * EPB + threadIdx.x * 16;   // 16 consecutive edges/thread
    int dc[16], sc[16];
    int cnt = 0;
    if (base + 16 <= N_EDGES) {
        #pragma unroll
        for (int j = 0; j < 4; ++j) {
            int4 d4 = *(const int4*)(dst + base + j * 4);
            int4 s4 = *(const int4*)(src + base + j * 4);
            dc[j * 4 + 0] = d4.x; dc[j * 4 + 1] = d4.y; dc[j * 4 + 2] = d4.z; dc[j * 4 + 3] = d4.w;
            sc[j * 4 + 0] = s4.x; sc[j * 4 + 1] = s4.y; sc[j * 4 + 2] = s4.z; sc[j * 4 + 3] = s4.w;
        }
        cnt = 16;
    } else if (base < N_EDGES) {
        cnt = (int)(N_EDGES - base);
        for (int j = 0; j < cnt; ++j) { dc[j] = dst[base + j]; sc[j] = src[base + j]; }
    }
    for (int j = 0; j < cnt; ++j) atomicAdd(&h[dc[j] >> BSHIFT], 1);
    __syncthreads();
    for (int j = threadIdx.x; j < NB; j += 256)
        start[j] = h[j] ? atomicAdd(&gCur[j], h[j]) : 0;
    __syncthreads();
    for (int j = 0; j < cnt; ++j) {
        int b = dc[j] >> BSHIFT;
        int p = atomicAdd(&start[b], 1);
        if (p < (b + 1) * CAP)                     // overflow clamp (P ~ 1e-16)
            bedges[p] = ((dc[j] & 255) << 24) | sc[j];
    }
}

// per-bucket LDS counting sort; int4 reads (CAP region is 16B-aligned + padded)
__global__ __launch_bounds__(256) void bucket_sort_kernel(const int* __restrict__ gCur,
                                                          const int* __restrict__ bedges,
                                                          int* __restrict__ csr,
                                                          int2* __restrict__ off2) {
    __shared__ int sdata[256];
    __shared__ int cur[256];
    int b = blockIdx.x, t = threadIdx.x;
    int r0 = b * CAP;
    int n = gCur[b] - r0;
    if (n > CAP) n = CAP;
    cur[t] = 0;
    __syncthreads();
    for (int k = t * 4; k < n; k += 1024) {
        int4 v4 = *(const int4*)(bedges + r0 + k);
        int m = n - k;
        atomicAdd(&cur[(unsigned)v4.x >> 24], 1);
        if (m > 1) atomicAdd(&cur[(unsigned)v4.y >> 24], 1);
        if (m > 2) atomicAdd(&cur[(unsigned)v4.z >> 24], 1);
        if (m > 3) atomicAdd(&cur[(unsigned)v4.w >> 24], 1);
    }
    __syncthreads();
    int c = cur[t];
    sdata[t] = c;
    __syncthreads();
    for (int d = 1; d < 256; d <<= 1) {
        int u = (t >= d) ? sdata[t - d] : 0;
        __syncthreads();
        sdata[t] += u;
        __syncthreads();
    }
    int ex = (t == 0) ? 0 : sdata[t - 1];
    off2[(b << BSHIFT) + t] = make_int2(r0 + ex, c);
    cur[t] = ex;
    __syncthreads();
    for (int k = t * 4; k < n; k += 1024) {
        int4 v4 = *(const int4*)(bedges + r0 + k);
        int m = n - k;
        {
            int p = atomicAdd(&cur[(unsigned)v4.x >> 24], 1);
            csr[r0 + p] = v4.x & 0xFFFFFF;
        }
        if (m > 1) {
            int p = atomicAdd(&cur[(unsigned)v4.y >> 24], 1);
            csr[r0 + p] = v4.y & 0xFFFFFF;
        }
        if (m > 2) {
            int p = atomicAdd(&cur[(unsigned)v4.z >> 24], 1);
            csr[r0 + p] = v4.z & 0xFFFFFF;
        }
        if (m > 3) {
            int p = atomicAdd(&cur[(unsigned)v4.w >> 24], 1);
            csr[r0 + p] = v4.w & 0xFFFFFF;
        }
    }
}

// ---------------- fused gather(x8) + MLP1 + BOTH layer-2 pretransforms ----------------
// 16 nodes/block, 16 lanes/node = 8 dim-slices x 2 edge-parities: serial edge
// chain halved, divergence pool 4 nodes/wave. Gather -> mtile (LDS).
// GEMM1: h = relu([mean|x]@W1+b1) -> htile (LDS only). Stage 2: g8 = fp8(h@W2_l).
// Stage 3: f2 = bf16(h@W2_r). h never touches HBM.
#define HSTRIDE 132   // 128-col bf16 rows, +4 pad breaks 256B bank stride
__global__ __launch_bounds__(256) void mfma_mlp_fused_kernel(
        const int2* __restrict__ off2, const int* __restrict__ csr_src,
        const uchar_t* __restrict__ x8,
        const ushort_t* __restrict__ Ax,
        const ushort_t* __restrict__ pack1, const float* __restrict__ bias,
        const ushort_t* __restrict__ pack2l, const ushort_t* __restrict__ pack2r,
        ushort_t* __restrict__ f2, uchar_t* __restrict__ g8) {
    __shared__ ushort_t mtile[16 * HSTRIDE];
    __shared__ ushort_t htile[16 * HSTRIDE];
    long m0b = (long)blockIdx.x * 16;
    // --- prologue: parity-split gather of 128-dim fp8 mean into LDS ---
    {
        int lane16 = threadIdx.x & 15;
        int d = lane16 & 7;                   // dim slice (16 dims / 16 B)
        int p = lane16 >> 3;                  // edge parity
        int local = threadIdx.x >> 4;         // node within block
        long i = m0b + local;                 // exact grid: always < N_NODES
        int2 bd = off2[i];
        int n = bd.y;
        const uchar_t* gbase = x8 + d * 16;
        f32x2 acc2[8];
        #pragma unroll
        for (int j = 0; j < 8; ++j) acc2[j] = (f32x2){0.f, 0.f};
        int np = (n + 1 - p) >> 1;            // #edges of this parity
        gather_acc_fp8n<7, 1, 8, 2>(gbase, csr_src + bd.x + p, np, acc2);
        float* pa = (float*)acc2;
        // combine parities: lane^8 = same node, same dim slice, other parity
        #pragma unroll
        for (int j = 0; j < 16; ++j) pa[j] += __shfl_xor(pa[j], 8);
        float inv = (n > 0) ? 1.f / (float)n : 0.f;
        // each lane writes 8 of its 16 dims (parity selects half)
        int dim0 = d * 16 + p * 8;
        uint_t o[4];
        #pragma unroll
        for (int j = 0; j < 4; ++j)
            o[j] = pack2bf(pa[p * 8 + j * 2] * inv, pa[p * 8 + j * 2 + 1] * inv);
        *(uint4*)(mtile + local * HSTRIDE + dim0) = *(uint4*)o;
    }
    __syncthreads();
    // --- GEMM1: h = relu([mean|x]@W1 + b1), 16 rows x 128 cols, K=256 ---
    // wave w computes cols [w*32, w*32+32)
    int lane = threadIdx.x & 63;
    int wave = threadIdx.x >> 6;
    int r = lane & 15;
    int quad = lane >> 4;
    long arow = m0b + r;

    bf16x8 areg[8];
    #pragma unroll
    for (int kt = 0; kt < 8; ++kt) {
        int k = (kt & 3) * 32 + quad * 8;
        areg[kt] = (kt < 4)
            ? *(const bf16x8*)(&mtile[r * HSTRIDE + k])
            : *(const bf16x8*)(Ax + arow * 128 + k);
    }

    f32x4 acc[2];
    #pragma unroll
    for (int nt = 0; nt < 2; ++nt) acc[nt] = (f32x4){0.f, 0.f, 0.f, 0.f};
    #pragma unroll
    for (int nt = 0; nt < 2; ++nt) {
        int gnt = wave * 2 + nt;
        #pragma unroll
        for (int kt = 0; kt < 8; ++kt) {
            bf16x8 bfrag = *(const bf16x8*)(pack1 + ((long)(gnt * 8 + kt) * 64 + lane) * 8);
            acc[nt] = __builtin_amdgcn_mfma_f32_16x16x32_bf16(areg[kt], bfrag, acc[nt], 0, 0, 0);
        }
    }

    // epilogue: h -> shared LDS tile (row = quad*4+q, col = wave*32+nt*16+r)
    #pragma unroll
    for (int nt = 0; nt < 2; ++nt) {
        int col = wave * 32 + nt * 16 + r;
        float bj = bias[col];
        #pragma unroll
        for (int q = 0; q < 4; ++q) {
            float v = fmaxf(acc[nt][q] + bj, 0.f);
            htile[(quad * 4 + q) * HSTRIDE + col] = f2bf(v);
        }
    }
    __syncthreads();   // htile cols span all waves; stages 2/3 read full K
    // --- stage 2: g8 = fp8(h @ W2_l), 16 rows x 64 cols; wave w -> cols [w*16,+16) ---
    bf16x8 areg2[4];
    #pragma unroll
    for (int kt = 0; kt < 4; ++kt)
        areg2[kt] = *(const bf16x8*)(&htile[r * HSTRIDE + kt * 32 + quad * 8]);
    f32x4 gacc = (f32x4){0.f, 0.f, 0.f, 0.f};
    #pragma unroll
    for (int kt = 0; kt < 4; ++kt) {
        bf16x8 bfrag = *(const bf16x8*)(pack2l + ((long)(wave * 4 + kt) * 64 + lane) * 8);
        gacc = __builtin_amdgcn_mfma_f32_16x16x32_bf16(areg2[kt], bfrag, gacc, 0, 0, 0);
    }
    {
        int col = wave * 16 + r;
        #pragma unroll
        for (int q = 0; q < 4; ++q) {
            long orow = m0b + quad * 4 + q;
            g8[orow * 64 + col] = f2fp8_byte(gacc[q]);
        }
    }
    // --- stage 3: f2 = bf16(h @ W2_r), 16 rows x 64 cols ---
    f32x4 facc = (f32x4){0.f, 0.f, 0.f, 0.f};
    #pragma unroll
    for (int kt = 0; kt < 4; ++kt) {
        bf16x8 bfrag = *(const bf16x8*)(pack2r + ((long)(wave * 4 + kt) * 64 + lane) * 8);
        facc = __builtin_amdgcn_mfma_f32_16x16x32_bf16(areg2[kt], bfrag, facc, 0, 0, 0);
    }
    {
        int col = wave * 16 + r;
        #pragma unroll
        for (int q = 0; q < 4; ++q) {
            long orow = m0b + quad * 4 + q;
            f2[orow * 64 + col] = f2bf(facc[q]);
        }
    }
}

// ---------------- final: pure gather(g8) + out = relu(mean + f2 + b2) ----------------
// 32 nodes/block, 8 lanes/node = 4 dim-slices x 2 edge-parities. Each thread sums
// every other edge; partial sums combined via shfl_xor(4). No LDS, no MFMA.
__global__ __launch_bounds__(256) void final_gather_kernel(
        const int2* __restrict__ off2, const int* __restrict__ csr_src,
        const uchar_t* __restrict__ g8,
        const ushort_t* __restrict__ f2, const float* __restrict__ b2,
        float* __restrict__ out) {
    int lane8 = threadIdx.x & 7;
    int d = lane8 & 3;                        // dim slice (16 dims / 16 B)
    int p = lane8 >> 2;                       // edge parity
    int local = threadIdx.x >> 3;
    long i = (long)blockIdx.x * 32 + local;   // exact grid: always < N_NODES
    int2 bd = off2[i];
    int n = bd.y;
    const uchar_t* base = g8 + d * 16;
    f32x2 acc2[8];
    #pragma unroll
    for (int j = 0; j < 8; ++j) acc2[j] = (f32x2){0.f, 0.f};
    int np = (n + 1 - p) >> 1;                // #edges of this parity
    gather_acc_fp8n<6, 1, 8, 2>(base, csr_src + bd.x + p, np, acc2);
    float* pa = (float*)acc2;
    // combine parities: lane^4 is the partner (same node, same dim slice)
    #pragma unroll
    for (int j = 0; j < 16; ++j) pa[j] += __shfl_xor(pa[j], 4);
    float inv = (n > 0) ? 1.f / (float)n : 0.f;
    // each lane writes 8 dims: [d*16 + p*8, +8)
    int dim0 = d * 16 + p * 8;
    ushort_t fu[8];
    *(uint4*)fu = *(const uint4*)(f2 + i * 64 + dim0);
    float o[8];
    #pragma unroll
    for (int j = 0; j < 8; ++j) {
        float m = bf2f(f2bf(pa[p * 8 + j] * inv));   // keep bf16-mean rounding
        o[j] = fmaxf(m + bf2f(fu[j]) + b2[dim0 + j], 0.f);
    }
    *(float4*)(out + i * 64 + dim0)     = make_float4(o[0], o[1], o[2], o[3]);
    *(float4*)(out + i * 64 + dim0 + 4) = make_float4(o[4], o[5], o[6], o[7]);
}

extern "C" void kernel_launch(void* const* d_in, const int* in_sizes, int n_in,
                              void* d_out, int out_size, void* d_ws, size_t ws_size,
                              hipStream_t stream) {
    const float* x    = (const float*)d_in[0];
    const int*   ei   = (const int*)d_in[1];
    const float* W1_l = (const float*)d_in[2];
    const float* W1_r = (const float*)d_in[3];
    const float* b1   = (const float*)d_in[4];
    const float* W2_l = (const float*)d_in[5];
    const float* W2_r = (const float*)d_in[6];
    const float* b2   = (const float*)d_in[7];
    float* out = (float*)d_out;

    const int* src = ei;
    const int* dst = ei + N_EDGES;

    // workspace layout (16B aligned). hb eliminated (h lives only in LDS);
    // f2 [N][64] bf16 carries the layer-2 self term.
    int*  gCur   = (int*)d_ws;                        // 512
    int2* off2   = (int2*)(gCur + 512);               // 100608 int2
    int*  bedges = (int*)(off2 + 100608);             // NB*CAP
    int*  csr    = bedges + NB * CAP;                 // NB*CAP
    ushort_t* xb = (ushort_t*)(csr + NB * CAP);       // 25.6 MB row-major [N][128] bf16
    uchar_t*  x8 = (uchar_t*)(xb + (long)N_NODES * 128); // 12.8 MB fp8 [N][128]
    ushort_t* f2 = (ushort_t*)(x8 + (long)N_NODES * 128); // 12.8 MB bf16 [N][64]
    ushort_t* pack1  = f2 + (long)N_NODES * 64;       // 256*128 bf16
    ushort_t* pack2l = pack1 + 256 * 128;             // 128*64
    ushort_t* pack2r = pack2l + 128 * 64;             // 128*64
    uchar_t*  g8     = (uchar_t*)(pack2r + 128 * 64); // 6.4 MB fp8 [N][64]

    // ---- fused prep: weight packs + cursor init + x->bf16/fp8 (1 launch) ----
    prep_kernel<<<26 + CVT_BLOCKS, 256, 0, stream>>>(
        W1_l, W1_r, pack1, W2_l, pack2l, W2_r, pack2r, gCur, x, xb, x8);

    // ---- CSR build (fixed-stride buckets) ----
    bucket_scatter_kernel<<<PART_BLOCKS, 256, 0, stream>>>(src, dst, gCur, bedges);
    bucket_sort_kernel<<<NB, 256, 0, stream>>>(gCur, bedges, csr, off2);

    // ---- layer 1 + layer-2 pretransforms (fully fused, 16 nodes/block,
    //      parity-split gather): mean = gather(x8) in LDS;
    //      h = relu([mean|x]@W1+b1) in LDS; g8 = fp8(h@W2_l); f2 = bf16(h@W2_r) ----
    mfma_mlp_fused_kernel<<<N_NODES / 16, 256, 0, stream>>>(
        off2, csr, x8, xb, pack1, b1, pack2l, pack2r, f2, g8);

    // ---- layer 2: out = relu(gather-mean(g8) + f2 + b2), pure gather ----
    final_gather_kernel<<<N_NODES / 32, 256, 0, stream>>>(
        off2, csr, g8, f2, b2, out);
}

// Round 6
// 224.514 us; speedup vs baseline: 1.0504x; 1.0504x over previous
//
#include <hip/hip_runtime.h>

#define N_NODES 100000
#define N_EDGES 1600000
#define D_IN 128
#define D_HID 128
#define D_LAT 64

#define BSHIFT 8                          // 256 nodes per bucket
#define NB 392                            // ceil(100352 / 256) buckets
#define CAP 4608                          // slots per bucket region (mean 4082 + 8.2 sigma)
#define EPB 4096                          // edges per partition block
#define PART_BLOCKS ((N_EDGES + EPB - 1) / EPB)   // 391
#define CVT_BLOCKS (((long)N_NODES * 128 / 16 + 255) / 256)   // 3125

typedef unsigned short ushort_t;
typedef unsigned int uint_t;
typedef unsigned char uchar_t;
using bf16x8 = __attribute__((ext_vector_type(8))) short;
using f32x4  = __attribute__((ext_vector_type(4))) float;
using f32x2  = __attribute__((ext_vector_type(2))) float;

__device__ inline ushort_t f2bf(float f) {
    uint_t u = __float_as_uint(f);
    return (ushort_t)((u + 0x7fffu + ((u >> 16) & 1u)) >> 16);   // RNE
}
__device__ inline uint_t pack2bf(float a, float b) {
    return (uint_t)f2bf(a) | ((uint_t)f2bf(b) << 16);
}
__device__ inline float bf2f(ushort_t u) {
    return __uint_as_float(((uint_t)u) << 16);
}

// ---------------- fp8 e4m3 helpers (word-select must be compile-time) ----------------
#if __has_builtin(__builtin_amdgcn_cvt_pk_f32_fp8) && __has_builtin(__builtin_amdgcn_cvt_pk_fp8_f32)
#define HW_FP8 1
template<bool HI>
__device__ inline f32x2 fp8pk2f(uint_t v) {
    return __builtin_amdgcn_cvt_pk_f32_fp8(v, HI);       // HI is an ICE here
}
__device__ inline uint_t f2fp8pk4(float a, float b, float c, float d) {
    uint_t w = __builtin_amdgcn_cvt_pk_fp8_f32(a, b, 0, false);
    w = __builtin_amdgcn_cvt_pk_fp8_f32(c, d, w, true);
    return w;
}
__device__ inline uchar_t f2fp8_byte(float f) {
    return (uchar_t)(__builtin_amdgcn_cvt_pk_fp8_f32(f, f, 0, false) & 0xff);
}
#else
// fallback: software e4m3fn (normals exact w/ RNE; subnormals flushed)
__device__ inline float fp8b2f(uint_t b) {
    uint_t em = b & 0x7f;
    if (em == 0) return 0.f;
    uint_t bits = ((em << 20) + (120u << 23)) | ((b & 0x80u) << 24);
    return __uint_as_float(bits);
}
template<bool HI>
__device__ inline f32x2 fp8pk2f(uint_t v) {
    uint_t w = HI ? (v >> 16) : v;
    f32x2 r; r.x = fp8b2f(w & 0xff); r.y = fp8b2f((w >> 8) & 0xff);
    return r;
}
__device__ inline uint_t f2fp8_1(float f) {
    uint_t u = __float_as_uint(f);
    uint_t s = (u >> 31) << 7;
    uint_t au = u & 0x7fffffff;
    if (au >= 0x43e00000u) return s | 0x7e;              // clamp to 448
    if (au < 0x3c000000u) return s;                      // < 2^-7 -> 0 (approx)
    uint_t r = au + 0x0007ffffu + ((au >> 20) & 1u);     // RNE at 3 mantissa bits
    return s | (((r >> 20) - (120u << 3)) & 0x7f);
}
__device__ inline uint_t f2fp8pk4(float a, float b, float c, float d) {
    return f2fp8_1(a) | (f2fp8_1(b) << 8) | (f2fp8_1(c) << 16) | (f2fp8_1(d) << 24);
}
__device__ inline uchar_t f2fp8_byte(float f) { return (uchar_t)f2fp8_1(f); }
#endif

// packed f32x2 accumulate: hipcc emits v_pk_add_f32; per-element order = scalar form.
__device__ inline void accf8x4p(f32x2* a, uint_t w, int b2) {
    a[b2]     += fp8pk2f<false>(w);
    a[b2 + 1] += fp8pk2f<true>(w);
}
__device__ inline void accf8x16p(f32x2* a, uint4 u) {
    accf8x4p(a, u.x, 0); accf8x4p(a, u.y, 2); accf8x4p(a, u.z, 4); accf8x4p(a, u.w, 6);
}

// ---------------- software-pipelined fp8 gather-accumulate ----------------
// RSHIFT = log2(row stride bytes); NV = uint4 chunks per row-slice per lane;
// DEPTH = edges in flight in the main loop; STRIDE = index stride (2 = parity).
// Main loop prefetches next batch's csr indices during the current batch's
// unpack VALU. Tail is a CASCADE (4/2/1) of exec-mask-guarded sub-batches:
// no wasted loads, no wasted unpack (vs the old full-DEPTH clamped tail).
// Per-element accumulation order identical to the serial form (ascending k).
template<int RSHIFT, int NV, int STRIDE, int D>
__device__ inline void gather_tail_step(const uchar_t* __restrict__ base,
                                        const int* __restrict__ idxp,
                                        int n, int& k, f32x2* acc) {
    if (k + D <= n) {                      // uniform within a node's lane group
        int idt[D];
        #pragma unroll
        for (int j = 0; j < D; ++j) idt[j] = idxp[(k + j) * STRIDE];
        uint4 u[D][NV];
        #pragma unroll
        for (int j = 0; j < D; ++j) {
            #pragma unroll
            for (int v = 0; v < NV; ++v)
                u[j][v] = *(const uint4*)(base + ((long)idt[j] << RSHIFT) + v * 16);
        }
        #pragma unroll
        for (int j = 0; j < D; ++j) {
            #pragma unroll
            for (int v = 0; v < NV; ++v)
                accf8x16p(acc + v * 8, u[j][v]);
        }
        k += D;
    }
}

template<int RSHIFT, int NV, int DEPTH, int STRIDE = 1>
__device__ inline void gather_acc_fp8n(const uchar_t* __restrict__ base,
                                       const int* __restrict__ idxp,
                                       int n, f32x2* acc) {
    int k = 0;
    int idx[DEPTH];
    if (n >= DEPTH) {
        #pragma unroll
        for (int j = 0; j < DEPTH; ++j) idx[j] = idxp[j * STRIDE];
    }
    while (k + DEPTH <= n) {
        uint4 u[DEPTH][NV];
        #pragma unroll
        for (int j = 0; j < DEPTH; ++j) {
            #pragma unroll
            for (int v = 0; v < NV; ++v)
                u[j][v] = *(const uint4*)(base + ((long)idx[j] << RSHIFT) + v * 16);
        }
        int kn = k + DEPTH;
        if (kn + DEPTH <= n) {
            #pragma unroll
            for (int j = 0; j < DEPTH; ++j) idx[j] = idxp[(kn + j) * STRIDE];
        }
        #pragma unroll
        for (int j = 0; j < DEPTH; ++j) {
            #pragma unroll
            for (int v = 0; v < NV; ++v)
                accf8x16p(acc + v * 8, u[j][v]);
        }
        k = kn;
    }
    // cascade tail: 4, 2, 1 (DEPTH=8 call sites)
    gather_tail_step<RSHIFT, NV, STRIDE, 4>(base, idxp, n, k, acc);
    gather_tail_step<RSHIFT, NV, STRIDE, 2>(base, idxp, n, k, acc);
    gather_tail_step<RSHIFT, NV, STRIDE, 1>(base, idxp, n, k, acc);
}

// ---------------- fused prep: weight packs + cursor init + x conversion ----------------
// blocks 0..15: pack1; 16..19: pack2l; 20..23: pack2r; 24..25: gCur; 26..: cvt x
__device__ inline void pack_w256(const float* Wl, const float* Wr, ushort_t* pack,
                                 int N, int tid) {
    int lane = tid & 63;
    int t = tid >> 6;
    int kt = t & 7;
    int nt = t >> 3;
    int n = nt * 16 + (lane & 15);
    int kbase = kt * 32 + (lane >> 4) * 8;
    ushort_t v[8];
    #pragma unroll
    for (int j = 0; j < 8; ++j) {
        int k = kbase + j;
        float w = (k < 128) ? Wl[k * N + n] : Wr[(k - 128) * N + n];
        v[j] = f2bf(w);
    }
    *(uint4*)(pack + (long)tid * 8) = *(uint4*)v;
}
__device__ inline void pack_w128(const float* W, ushort_t* pack, int N, int tid) {
    int lane = tid & 63;
    int t = tid >> 6;
    int kt = t & 3;
    int nt = t >> 2;
    int n = nt * 16 + (lane & 15);
    int kbase = kt * 32 + (lane >> 4) * 8;
    ushort_t v[8];
    #pragma unroll
    for (int j = 0; j < 8; ++j) v[j] = f2bf(W[(kbase + j) * N + n]);
    *(uint4*)(pack + (long)tid * 8) = *(uint4*)v;
}

__global__ __launch_bounds__(256) void prep_kernel(
        const float* __restrict__ W1_l, const float* __restrict__ W1_r,
        ushort_t* __restrict__ pack1,
        const float* __restrict__ W2_l, ushort_t* __restrict__ pack2l,
        const float* __restrict__ W2_r, ushort_t* __restrict__ pack2r,
        int* __restrict__ gCur,
        const float* __restrict__ x, ushort_t* __restrict__ xb,
        uchar_t* __restrict__ x8) {
    int b = blockIdx.x;
    if (b < 16) {
        pack_w256(W1_l, W1_r, pack1, 128, b * 256 + threadIdx.x);
    } else if (b < 20) {
        pack_w128(W2_l, pack2l, 64, (b - 16) * 256 + threadIdx.x);
    } else if (b < 24) {
        pack_w128(W2_r, pack2r, 64, (b - 20) * 256 + threadIdx.x);
    } else if (b < 26) {
        int t = (b - 24) * 256 + threadIdx.x;
        if (t < NB) gCur[t] = t * CAP;
    } else {
        long i = ((long)(b - 26) * 256 + threadIdx.x) * 16;
        if (i >= (long)N_NODES * 128) return;
        float4 a = *(const float4*)(x + i);
        float4 bb = *(const float4*)(x + i + 4);
        float4 c = *(const float4*)(x + i + 8);
        float4 d = *(const float4*)(x + i + 12);
        uint4 ob0, ob1;
        ob0.x = pack2bf(a.x, a.y);  ob0.y = pack2bf(a.z, a.w);
        ob0.z = pack2bf(bb.x, bb.y); ob0.w = pack2bf(bb.z, bb.w);
        ob1.x = pack2bf(c.x, c.y);  ob1.y = pack2bf(c.z, c.w);
        ob1.z = pack2bf(d.x, d.y);  ob1.w = pack2bf(d.z, d.w);
        *(uint4*)(xb + i) = ob0;
        *(uint4*)(xb + i + 8) = ob1;
        uint4 o8;
        o8.x = f2fp8pk4(a.x, a.y, a.z, a.w);
        o8.y = f2fp8pk4(bb.x, bb.y, bb.z, bb.w);
        o8.z = f2fp8pk4(c.x, c.y, c.z, c.w);
        o8.w = f2fp8pk4(d.x, d.y, d.z, d.w);
        *(uint4*)(x8 + i) = o8;
    }
}

// ---------------- CSR build: fixed-stride bucketed counting sort ----------------
__global__ __launch_bounds__(256) void bucket_scatter_kernel(const int* __restrict__ src,
                                                             const int* __restrict__ dst,
                                                             int* __restrict__ gCur,
                                                             int* __restrict__ bedges) {
    __shared__ int h[NB];
    __shared__ int start[NB];
    for (int j = threadIdx.x; j < NB; j += 256) h[j] = 0;
    __syncthreads();
    long base = (long)blockIdx.x * EPB + threadIdx.x * 16;   // 16 consecutive edges/thread
    int dc[16], sc[16];
    int cnt = 0;
    if (base + 16 <= N_EDGES) {
        #pragma unroll
        for (int j = 0; j < 4; ++j) {
            int4 d4 = *(const int4*)(dst + base + j * 4);
            int4 s4 = *(const int4*)(src + base + j * 4);
            dc[j * 4 + 0] = d4.x; dc[j * 4 + 1] = d4.y; dc[j * 4 + 2] = d4.z; dc[j * 4 + 3] = d4.w;
            sc[j * 4 + 0] = s4.x; sc[j * 4 + 1] = s4.y; sc[j * 4 + 2] = s4.z; sc[j * 4 + 3] = s4.w;
        }
        cnt = 16;
    } else if (base < N_EDGES) {
        cnt = (int)(N_EDGES - base);
        for (int j = 0; j < cnt; ++j) { dc[j] = dst[base + j]; sc[j] = src[base + j]; }
    }
    for (int j = 0; j < cnt; ++j) atomicAdd(&h[dc[j] >> BSHIFT], 1);
    __syncthreads();
    for (int j = threadIdx.x; j < NB; j += 256)
        start[j] = h[j] ? atomicAdd(&gCur[j], h[j]) : 0;
    __syncthreads();
    for (int j = 0; j < cnt; ++j) {
        int b = dc[j] >> BSHIFT;
        int p = atomicAdd(&start[b], 1);
        if (p < (b + 1) * CAP)                     // overflow clamp (P ~ 1e-16)
            bedges[p] = ((dc[j] & 255) << 24) | sc[j];
    }
}

// per-bucket LDS counting sort; int4 reads (CAP region is 16B-aligned + padded)
__global__ __launch_bounds__(256) void bucket_sort_kernel(const int* __restrict__ gCur,
                                                          const int* __restrict__ bedges,
                                                          int* __restrict__ csr,
                                                          int2* __restrict__ off2) {
    __shared__ int sdata[256];
    __shared__ int cur[256];
    int b = blockIdx.x, t = threadIdx.x;
    int r0 = b * CAP;
    int n = gCur[b] - r0;
    if (n > CAP) n = CAP;
    cur[t] = 0;
    __syncthreads();
    for (int k = t * 4; k < n; k += 1024) {
        int4 v4 = *(const int4*)(bedges + r0 + k);
        int m = n - k;
        atomicAdd(&cur[(unsigned)v4.x >> 24], 1);
        if (m > 1) atomicAdd(&cur[(unsigned)v4.y >> 24], 1);
        if (m > 2) atomicAdd(&cur[(unsigned)v4.z >> 24], 1);
        if (m > 3) atomicAdd(&cur[(unsigned)v4.w >> 24], 1);
    }
    __syncthreads();
    int c = cur[t];
    sdata[t] = c;
    __syncthreads();
    for (int d = 1; d < 256; d <<= 1) {
        int u = (t >= d) ? sdata[t - d] : 0;
        __syncthreads();
        sdata[t] += u;
        __syncthreads();
    }
    int ex = (t == 0) ? 0 : sdata[t - 1];
    off2[(b << BSHIFT) + t] = make_int2(r0 + ex, c);
    cur[t] = ex;
    __syncthreads();
    for (int k = t * 4; k < n; k += 1024) {
        int4 v4 = *(const int4*)(bedges + r0 + k);
        int m = n - k;
        {
            int p = atomicAdd(&cur[(unsigned)v4.x >> 24], 1);
            csr[r0 + p] = v4.x & 0xFFFFFF;
        }
        if (m > 1) {
            int p = atomicAdd(&cur[(unsigned)v4.y >> 24], 1);
            csr[r0 + p] = v4.y & 0xFFFFFF;
        }
        if (m > 2) {
            int p = atomicAdd(&cur[(unsigned)v4.z >> 24], 1);
            csr[r0 + p] = v4.z & 0xFFFFFF;
        }
        if (m > 3) {
            int p = atomicAdd(&cur[(unsigned)v4.w >> 24], 1);
            csr[r0 + p] = v4.w & 0xFFFFFF;
        }
    }
}

// ---------------- fused gather(x8) + MLP1 + BOTH layer-2 pretransforms ----------------
// 32 nodes/block, 8 lanes/node (empirically optimal for 128-B rows). Gather ->
// mtile (LDS). GEMM1: h = relu([mean|x]@W1+b1) -> htile (LDS only).
// Stage 2: g8 = fp8(h@W2_l). Stage 3: f2 = bf16(h@W2_r). h never touches HBM.
#define HSTRIDE 132   // 128-col bf16 rows, +4 pad breaks 256B bank stride
__global__ __launch_bounds__(256) void mfma_mlp_fused_kernel(
        const int2* __restrict__ off2, const int* __restrict__ csr_src,
        const uchar_t* __restrict__ x8,
        const ushort_t* __restrict__ Ax,
        const ushort_t* __restrict__ pack1, const float* __restrict__ bias,
        const ushort_t* __restrict__ pack2l, const ushort_t* __restrict__ pack2r,
        ushort_t* __restrict__ f2, uchar_t* __restrict__ g8) {
    __shared__ ushort_t mtile[32 * HSTRIDE];
    __shared__ ushort_t htile[32 * HSTRIDE];
    long m0b = (long)blockIdx.x * 32;
    // --- prologue: gather 128-dim fp8 mean for this block's 32 rows into LDS ---
    {
        int lane8 = threadIdx.x & 7;          // 16 dims (16 B) per lane
        int local = threadIdx.x >> 3;         // node within block
        long i = m0b + local;                 // exact grid: always < N_NODES
        int2 bd = off2[i];
        const uchar_t* gbase = x8 + lane8 * 16;
        f32x2 acc2[8];
        #pragma unroll
        for (int j = 0; j < 8; ++j) acc2[j] = (f32x2){0.f, 0.f};
        gather_acc_fp8n<7, 1, 8, 1>(gbase, csr_src + bd.x, bd.y, acc2);
        float* pa = (float*)acc2;
        float inv = (bd.y > 0) ? 1.f / (float)bd.y : 0.f;
        uint4 o0, o1;
        o0.x = pack2bf(pa[0] * inv,  pa[1] * inv);
        o0.y = pack2bf(pa[2] * inv,  pa[3] * inv);
        o0.z = pack2bf(pa[4] * inv,  pa[5] * inv);
        o0.w = pack2bf(pa[6] * inv,  pa[7] * inv);
        o1.x = pack2bf(pa[8] * inv,  pa[9] * inv);
        o1.y = pack2bf(pa[10] * inv, pa[11] * inv);
        o1.z = pack2bf(pa[12] * inv, pa[13] * inv);
        o1.w = pack2bf(pa[14] * inv, pa[15] * inv);
        ushort_t* mp = mtile + local * HSTRIDE + lane8 * 16;
        *(uint4*)mp = o0;
        *(uint4*)(mp + 8) = o1;
    }
    __syncthreads();
    // --- GEMM1: h = relu([mean|x]@W1 + b1), 32 rows x 128 cols, K=256 ---
    int lane = threadIdx.x & 63;
    int wave = threadIdx.x >> 6;
    int wr = wave & 1;                        // row group (16 rows)
    int wc = wave >> 1;                       // col group (64 cols)
    int r = lane & 15;
    int quad = lane >> 4;
    int rowl = wr * 16 + r;
    long arow = m0b + rowl;

    bf16x8 areg[8];
    #pragma unroll
    for (int kt = 0; kt < 8; ++kt) {
        int k = (kt & 3) * 32 + quad * 8;
        areg[kt] = (kt < 4)
            ? *(const bf16x8*)(&mtile[rowl * HSTRIDE + k])
            : *(const bf16x8*)(Ax + arow * 128 + k);
    }

    f32x4 acc[4];
    #pragma unroll
    for (int nt = 0; nt < 4; ++nt) acc[nt] = (f32x4){0.f, 0.f, 0.f, 0.f};
    #pragma unroll
    for (int nt = 0; nt < 4; ++nt) {
        int gnt = wc * 4 + nt;
        #pragma unroll
        for (int kt = 0; kt < 8; ++kt) {
            bf16x8 bfrag = *(const bf16x8*)(pack1 + ((long)(gnt * 8 + kt) * 64 + lane) * 8);
            acc[nt] = __builtin_amdgcn_mfma_f32_16x16x32_bf16(areg[kt], bfrag, acc[nt], 0, 0, 0);
        }
    }

    // epilogue: h -> shared LDS tile (row = wr*16+quad*4+q, col = wc*64+nt*16+r)
    #pragma unroll
    for (int nt = 0; nt < 4; ++nt) {
        int col = wc * 64 + nt * 16 + r;
        float bj = bias[col];
        #pragma unroll
        for (int q = 0; q < 4; ++q) {
            float v = fmaxf(acc[nt][q] + bj, 0.f);
            htile[(wr * 16 + quad * 4 + q) * HSTRIDE + col] = f2bf(v);
        }
    }
    __syncthreads();   // htile cols span both col-groups; stages 2/3 read full K
    // --- stage 2: g8 = fp8(h @ W2_l), 32 rows x 64 cols, K=128 ---
    bf16x8 areg2[4];
    #pragma unroll
    for (int kt = 0; kt < 4; ++kt)
        areg2[kt] = *(const bf16x8*)(&htile[rowl * HSTRIDE + kt * 32 + quad * 8]);
    f32x4 gacc[2];
    #pragma unroll
    for (int nt = 0; nt < 2; ++nt) gacc[nt] = (f32x4){0.f, 0.f, 0.f, 0.f};
    #pragma unroll
    for (int nt = 0; nt < 2; ++nt) {
        int gnt = wc * 2 + nt;
        #pragma unroll
        for (int kt = 0; kt < 4; ++kt) {
            bf16x8 bfrag = *(const bf16x8*)(pack2l + ((long)(gnt * 4 + kt) * 64 + lane) * 8);
            gacc[nt] = __builtin_amdgcn_mfma_f32_16x16x32_bf16(areg2[kt], bfrag, gacc[nt], 0, 0, 0);
        }
    }
    #pragma unroll
    for (int nt = 0; nt < 2; ++nt) {
        int col = wc * 32 + nt * 16 + r;
        #pragma unroll
        for (int q = 0; q < 4; ++q) {
            long orow = m0b + wr * 16 + quad * 4 + q;
            g8[orow * 64 + col] = f2fp8_byte(gacc[nt][q]);
        }
    }
    // --- stage 3: f2 = bf16(h @ W2_r), 32 rows x 64 cols, K=128 ---
    f32x4 facc[2];
    #pragma unroll
    for (int nt = 0; nt < 2; ++nt) facc[nt] = (f32x4){0.f, 0.f, 0.f, 0.f};
    #pragma unroll
    for (int nt = 0; nt < 2; ++nt) {
        int gnt = wc * 2 + nt;
        #pragma unroll
        for (int kt = 0; kt < 4; ++kt) {
            bf16x8 bfrag = *(const bf16x8*)(pack2r + ((long)(gnt * 4 + kt) * 64 + lane) * 8);
            facc[nt] = __builtin_amdgcn_mfma_f32_16x16x32_bf16(areg2[kt], bfrag, facc[nt], 0, 0, 0);
        }
    }
    #pragma unroll
    for (int nt = 0; nt < 2; ++nt) {
        int col = wc * 32 + nt * 16 + r;
        #pragma unroll
        for (int q = 0; q < 4; ++q) {
            long orow = m0b + wr * 16 + quad * 4 + q;
            f2[orow * 64 + col] = f2bf(facc[nt][q]);
        }
    }
}

// ---------------- final: pure gather(g8) + out = relu(mean + f2 + b2) ----------------
// 32 nodes/block, 8 lanes/node = 4 dim-slices x 2 edge-parities. Each thread sums
// every other edge; partial sums combined via shfl_xor(4). No LDS, no MFMA.
__global__ __launch_bounds__(256) void final_gather_kernel(
        const int2* __restrict__ off2, const int* __restrict__ csr_src,
        const uchar_t* __restrict__ g8,
        const ushort_t* __restrict__ f2, const float* __restrict__ b2,
        float* __restrict__ out) {
    int lane8 = threadIdx.x & 7;
    int d = lane8 & 3;                        // dim slice (16 dims / 16 B)
    int p = lane8 >> 2;                       // edge parity
    int local = threadIdx.x >> 3;
    long i = (long)blockIdx.x * 32 + local;   // exact grid: always < N_NODES
    int2 bd = off2[i];
    int n = bd.y;
    const uchar_t* base = g8 + d * 16;
    f32x2 acc2[8];
    #pragma unroll
    for (int j = 0; j < 8; ++j) acc2[j] = (f32x2){0.f, 0.f};
    int np = (n + 1 - p) >> 1;                // #edges of this parity
    gather_acc_fp8n<6, 1, 8, 2>(base, csr_src + bd.x + p, np, acc2);
    float* pa = (float*)acc2;
    // combine parities: lane^4 is the partner (same node, same dim slice)
    #pragma unroll
    for (int j = 0; j < 16; ++j) pa[j] += __shfl_xor(pa[j], 4);
    float inv = (n > 0) ? 1.f / (float)n : 0.f;
    // each lane writes 8 dims: [d*16 + p*8, +8)
    int dim0 = d * 16 + p * 8;
    ushort_t fu[8];
    *(uint4*)fu = *(const uint4*)(f2 + i * 64 + dim0);
    float o[8];
    #pragma unroll
    for (int j = 0; j < 8; ++j) {
        float m = bf2f(f2bf(pa[p * 8 + j] * inv));   // keep bf16-mean rounding
        o[j] = fmaxf(m + bf2f(fu[j]) + b2[dim0 + j], 0.f);
    }
    *(float4*)(out + i * 64 + dim0)     = make_float4(o[0], o[1], o[2], o[3]);
    *(float4*)(out + i * 64 + dim0 + 4) = make_float4(o[4], o[5], o[6], o[7]);
}

extern "C" void kernel_launch(void* const* d_in, const int* in_sizes, int n_in,
                              void* d_out, int out_size, void* d_ws, size_t ws_size,
                              hipStream_t stream) {
    const float* x    = (const float*)d_in[0];
    const int*   ei   = (const int*)d_in[1];
    const float* W1_l = (const float*)d_in[2];
    const float* W1_r = (const float*)d_in[3];
    const float* b1   = (const float*)d_in[4];
    const float* W2_l = (const float*)d_in[5];
    const float* W2_r = (const float*)d_in[6];
    const float* b2   = (const float*)d_in[7];
    float* out = (float*)d_out;

    const int* src = ei;
    const int* dst = ei + N_EDGES;

    // workspace layout (16B aligned). hb eliminated (h lives only in LDS);
    // f2 [N][64] bf16 carries the layer-2 self term.
    int*  gCur   = (int*)d_ws;                        // 512
    int2* off2   = (int2*)(gCur + 512);               // 100608 int2
    int*  bedges = (int*)(off2 + 100608);             // NB*CAP
    int*  csr    = bedges + NB * CAP;                 // NB*CAP
    ushort_t* xb = (ushort_t*)(csr + NB * CAP);       // 25.6 MB row-major [N][128] bf16
    uchar_t*  x8 = (uchar_t*)(xb + (long)N_NODES * 128); // 12.8 MB fp8 [N][128]
    ushort_t* f2 = (ushort_t*)(x8 + (long)N_NODES * 128); // 12.8 MB bf16 [N][64]
    ushort_t* pack1  = f2 + (long)N_NODES * 64;       // 256*128 bf16
    ushort_t* pack2l = pack1 + 256 * 128;             // 128*64
    ushort_t* pack2r = pack2l + 128 * 64;             // 128*64
    uchar_t*  g8     = (uchar_t*)(pack2r + 128 * 64); // 6.4 MB fp8 [N][64]

    // ---- fused prep: weight packs + cursor init + x->bf16/fp8 (1 launch) ----
    prep_kernel<<<26 + CVT_BLOCKS, 256, 0, stream>>>(
        W1_l, W1_r, pack1, W2_l, pack2l, W2_r, pack2r, gCur, x, xb, x8);

    // ---- CSR build (fixed-stride buckets) ----
    bucket_scatter_kernel<<<PART_BLOCKS, 256, 0, stream>>>(src, dst, gCur, bedges);
    bucket_sort_kernel<<<NB, 256, 0, stream>>>(gCur, bedges, csr, off2);

    // ---- layer 1 + layer-2 pretransforms (fully fused, 32 nodes/block):
    //      mean = gather(x8) in LDS; h = relu([mean|x]@W1+b1) in LDS;
    //      g8 = fp8(h@W2_l); f2 = bf16(h@W2_r) ----
    mfma_mlp_fused_kernel<<<N_NODES / 32, 256, 0, stream>>>(
        off2, csr, x8, xb, pack1, b1, pack2l, pack2r, f2, g8);

    // ---- layer 2: out = relu(gather-mean(g8) + f2 + b2), pure gather ----
    final_gather_kernel<<<N_NODES / 32, 256, 0, stream>>>(
        off2, csr, g8, f2, b2, out);
}

// Round 7
// 222.501 us; speedup vs baseline: 1.0599x; 1.0090x over previous
//
#include <hip/hip_runtime.h>

#define N_NODES 100000
#define N_EDGES 1600000
#define D_IN 128
#define D_HID 128
#define D_LAT 64

#define BSHIFT 8                          // 256 nodes per bucket
#define NB 392                            // ceil(100352 / 256) buckets
#define CAP 4608                          // slots per bucket region (mean 4082 + 8.2 sigma)
#define EPB 4096                          // edges per partition block
#define PART_BLOCKS ((N_EDGES + EPB - 1) / EPB)   // 391
#define CVT_BLOCKS (((long)N_NODES * 128 / 16 + 255) / 256)   // 3125
// merged prep block layout: [0,391) scatter | [391,407) pack1 | [407,411) pack2l
//                           | [411,415) pack2r | [415, 415+3125) cvt x
#define PK1_BASE PART_BLOCKS
#define PK2L_BASE (PK1_BASE + 16)
#define PK2R_BASE (PK2L_BASE + 4)
#define CVT_BASE (PK2R_BASE + 4)

typedef unsigned short ushort_t;
typedef unsigned int uint_t;
typedef unsigned char uchar_t;
using bf16x8 = __attribute__((ext_vector_type(8))) short;
using f32x4  = __attribute__((ext_vector_type(4))) float;
using f32x2  = __attribute__((ext_vector_type(2))) float;

__device__ inline ushort_t f2bf(float f) {
    uint_t u = __float_as_uint(f);
    return (ushort_t)((u + 0x7fffu + ((u >> 16) & 1u)) >> 16);   // RNE
}
__device__ inline uint_t pack2bf(float a, float b) {
    return (uint_t)f2bf(a) | ((uint_t)f2bf(b) << 16);
}
__device__ inline float bf2f(ushort_t u) {
    return __uint_as_float(((uint_t)u) << 16);
}

// ---------------- fp8 e4m3 helpers (word-select must be compile-time) ----------------
#if __has_builtin(__builtin_amdgcn_cvt_pk_f32_fp8) && __has_builtin(__builtin_amdgcn_cvt_pk_fp8_f32)
#define HW_FP8 1
template<bool HI>
__device__ inline f32x2 fp8pk2f(uint_t v) {
    return __builtin_amdgcn_cvt_pk_f32_fp8(v, HI);       // HI is an ICE here
}
__device__ inline uint_t f2fp8pk4(float a, float b, float c, float d) {
    uint_t w = __builtin_amdgcn_cvt_pk_fp8_f32(a, b, 0, false);
    w = __builtin_amdgcn_cvt_pk_fp8_f32(c, d, w, true);
    return w;
}
__device__ inline uchar_t f2fp8_byte(float f) {
    return (uchar_t)(__builtin_amdgcn_cvt_pk_fp8_f32(f, f, 0, false) & 0xff);
}
#else
// fallback: software e4m3fn (normals exact w/ RNE; subnormals flushed)
__device__ inline float fp8b2f(uint_t b) {
    uint_t em = b & 0x7f;
    if (em == 0) return 0.f;
    uint_t bits = ((em << 20) + (120u << 23)) | ((b & 0x80u) << 24);
    return __uint_as_float(bits);
}
template<bool HI>
__device__ inline f32x2 fp8pk2f(uint_t v) {
    uint_t w = HI ? (v >> 16) : v;
    f32x2 r; r.x = fp8b2f(w & 0xff); r.y = fp8b2f((w >> 8) & 0xff);
    return r;
}
__device__ inline uint_t f2fp8_1(float f) {
    uint_t u = __float_as_uint(f);
    uint_t s = (u >> 31) << 7;
    uint_t au = u & 0x7fffffff;
    if (au >= 0x43e00000u) return s | 0x7e;              // clamp to 448
    if (au < 0x3c000000u) return s;                      // < 2^-7 -> 0 (approx)
    uint_t r = au + 0x0007ffffu + ((au >> 20) & 1u);     // RNE at 3 mantissa bits
    return s | (((r >> 20) - (120u << 3)) & 0x7f);
}
__device__ inline uint_t f2fp8pk4(float a, float b, float c, float d) {
    return f2fp8_1(a) | (f2fp8_1(b) << 8) | (f2fp8_1(c) << 16) | (f2fp8_1(d) << 24);
}
__device__ inline uchar_t f2fp8_byte(float f) { return (uchar_t)f2fp8_1(f); }
#endif

// packed f32x2 accumulate: hipcc emits v_pk_add_f32; per-element order = scalar form.
__device__ inline void accf8x4p(f32x2* a, uint_t w, int b2) {
    a[b2]     += fp8pk2f<false>(w);
    a[b2 + 1] += fp8pk2f<true>(w);
}
__device__ inline void accf8x16p(f32x2* a, uint4 u) {
    accf8x4p(a, u.x, 0); accf8x4p(a, u.y, 2); accf8x4p(a, u.z, 4); accf8x4p(a, u.w, 6);
}

// ---------------- software-pipelined fp8 gather-accumulate ----------------
// RSHIFT = log2(row stride bytes); NV = uint4 chunks per row-slice per lane;
// DEPTH = edges in flight in the main loop; STRIDE = index stride (2 = parity).
// Main loop prefetches next batch's csr indices during the current batch's
// unpack VALU. Tail is a CASCADE (4/2/1) of exec-mask-guarded sub-batches.
// Per-element accumulation order identical to the serial form (ascending k).
template<int RSHIFT, int NV, int STRIDE, int D>
__device__ inline void gather_tail_step(const uchar_t* __restrict__ base,
                                        const int* __restrict__ idxp,
                                        int n, int& k, f32x2* acc) {
    if (k + D <= n) {                      // uniform within a node's lane group
        int idt[D];
        #pragma unroll
        for (int j = 0; j < D; ++j) idt[j] = idxp[(k + j) * STRIDE];
        uint4 u[D][NV];
        #pragma unroll
        for (int j = 0; j < D; ++j) {
            #pragma unroll
            for (int v = 0; v < NV; ++v)
                u[j][v] = *(const uint4*)(base + ((long)idt[j] << RSHIFT) + v * 16);
        }
        #pragma unroll
        for (int j = 0; j < D; ++j) {
            #pragma unroll
            for (int v = 0; v < NV; ++v)
                accf8x16p(acc + v * 8, u[j][v]);
        }
        k += D;
    }
}

template<int RSHIFT, int NV, int DEPTH, int STRIDE = 1>
__device__ inline void gather_acc_fp8n(const uchar_t* __restrict__ base,
                                       const int* __restrict__ idxp,
                                       int n, f32x2* acc) {
    int k = 0;
    int idx[DEPTH];
    if (n >= DEPTH) {
        #pragma unroll
        for (int j = 0; j < DEPTH; ++j) idx[j] = idxp[j * STRIDE];
    }
    while (k + DEPTH <= n) {
        uint4 u[DEPTH][NV];
        #pragma unroll
        for (int j = 0; j < DEPTH; ++j) {
            #pragma unroll
            for (int v = 0; v < NV; ++v)
                u[j][v] = *(const uint4*)(base + ((long)idx[j] << RSHIFT) + v * 16);
        }
        int kn = k + DEPTH;
        if (kn + DEPTH <= n) {
            #pragma unroll
            for (int j = 0; j < DEPTH; ++j) idx[j] = idxp[(kn + j) * STRIDE];
        }
        #pragma unroll
        for (int j = 0; j < DEPTH; ++j) {
            #pragma unroll
            for (int v = 0; v < NV; ++v)
                accf8x16p(acc + v * 8, u[j][v]);
        }
        k = kn;
    }
    // cascade tail: 4, 2, 1 (DEPTH=8 call sites)
    gather_tail_step<RSHIFT, NV, STRIDE, 4>(base, idxp, n, k, acc);
    gather_tail_step<RSHIFT, NV, STRIDE, 2>(base, idxp, n, k, acc);
    gather_tail_step<RSHIFT, NV, STRIDE, 1>(base, idxp, n, k, acc);
}

// ---------------- merged prep: edge scatter + weight packs + x conversion ----------------
__device__ inline void pack_w256(const float* Wl, const float* Wr, ushort_t* pack,
                                 int N, int tid) {
    int lane = tid & 63;
    int t = tid >> 6;
    int kt = t & 7;
    int nt = t >> 3;
    int n = nt * 16 + (lane & 15);
    int kbase = kt * 32 + (lane >> 4) * 8;
    ushort_t v[8];
    #pragma unroll
    for (int j = 0; j < 8; ++j) {
        int k = kbase + j;
        float w = (k < 128) ? Wl[k * N + n] : Wr[(k - 128) * N + n];
        v[j] = f2bf(w);
    }
    *(uint4*)(pack + (long)tid * 8) = *(uint4*)v;
}
__device__ inline void pack_w128(const float* W, ushort_t* pack, int N, int tid) {
    int lane = tid & 63;
    int t = tid >> 6;
    int kt = t & 3;
    int nt = t >> 2;
    int n = nt * 16 + (lane & 15);
    int kbase = kt * 32 + (lane >> 4) * 8;
    ushort_t v[8];
    #pragma unroll
    for (int j = 0; j < 8; ++j) v[j] = f2bf(W[(kbase + j) * N + n]);
    *(uint4*)(pack + (long)tid * 8) = *(uint4*)v;
}

// gCurRel is the RELATIVE per-bucket cursor (zeroed by hipMemsetAsync before
// launch), so the scatter blocks need no ordering vs the rest of prep.
__global__ __launch_bounds__(256) void prep_kernel(
        const int* __restrict__ src, const int* __restrict__ dst,
        int* __restrict__ gCurRel, int* __restrict__ bedges,
        const float* __restrict__ W1_l, const float* __restrict__ W1_r,
        ushort_t* __restrict__ pack1,
        const float* __restrict__ W2_l, ushort_t* __restrict__ pack2l,
        const float* __restrict__ W2_r, ushort_t* __restrict__ pack2r,
        const float* __restrict__ x, ushort_t* __restrict__ xb,
        uchar_t* __restrict__ x8) {
    int b = blockIdx.x;
    if (b < PART_BLOCKS) {
        // ---- bucket scatter (fixed-stride bucketed counting sort, pass 1) ----
        __shared__ int h[NB];
        __shared__ int start[NB];
        for (int j = threadIdx.x; j < NB; j += 256) h[j] = 0;
        __syncthreads();
        long base = (long)b * EPB + threadIdx.x * 16;   // 16 consecutive edges/thread
        int dc[16], sc[16];
        int cnt = 0;
        if (base + 16 <= N_EDGES) {
            #pragma unroll
            for (int j = 0; j < 4; ++j) {
                int4 d4 = *(const int4*)(dst + base + j * 4);
                int4 s4 = *(const int4*)(src + base + j * 4);
                dc[j * 4 + 0] = d4.x; dc[j * 4 + 1] = d4.y; dc[j * 4 + 2] = d4.z; dc[j * 4 + 3] = d4.w;
                sc[j * 4 + 0] = s4.x; sc[j * 4 + 1] = s4.y; sc[j * 4 + 2] = s4.z; sc[j * 4 + 3] = s4.w;
            }
            cnt = 16;
        } else if (base < N_EDGES) {
            cnt = (int)(N_EDGES - base);
            for (int j = 0; j < cnt; ++j) { dc[j] = dst[base + j]; sc[j] = src[base + j]; }
        }
        for (int j = 0; j < cnt; ++j) atomicAdd(&h[dc[j] >> BSHIFT], 1);
        __syncthreads();
        for (int j = threadIdx.x; j < NB; j += 256)
            start[j] = h[j] ? (j * CAP + atomicAdd(&gCurRel[j], h[j])) : 0;
        __syncthreads();
        for (int j = 0; j < cnt; ++j) {
            int bk = dc[j] >> BSHIFT;
            int p = atomicAdd(&start[bk], 1);
            if (p < (bk + 1) * CAP)                    // overflow clamp (P ~ 1e-16)
                bedges[p] = ((dc[j] & 255) << 24) | sc[j];
        }
    } else if (b < PK2L_BASE) {
        pack_w256(W1_l, W1_r, pack1, 128, (b - PK1_BASE) * 256 + threadIdx.x);
    } else if (b < PK2R_BASE) {
        pack_w128(W2_l, pack2l, 64, (b - PK2L_BASE) * 256 + threadIdx.x);
    } else if (b < CVT_BASE) {
        pack_w128(W2_r, pack2r, 64, (b - PK2R_BASE) * 256 + threadIdx.x);
    } else {
        long i = ((long)(b - CVT_BASE) * 256 + threadIdx.x) * 16;
        if (i >= (long)N_NODES * 128) return;
        float4 a = *(const float4*)(x + i);
        float4 bb = *(const float4*)(x + i + 4);
        float4 c = *(const float4*)(x + i + 8);
        float4 d = *(const float4*)(x + i + 12);
        uint4 ob0, ob1;
        ob0.x = pack2bf(a.x, a.y);  ob0.y = pack2bf(a.z, a.w);
        ob0.z = pack2bf(bb.x, bb.y); ob0.w = pack2bf(bb.z, bb.w);
        ob1.x = pack2bf(c.x, c.y);  ob1.y = pack2bf(c.z, c.w);
        ob1.z = pack2bf(d.x, d.y);  ob1.w = pack2bf(d.z, d.w);
        *(uint4*)(xb + i) = ob0;
        *(uint4*)(xb + i + 8) = ob1;
        uint4 o8;
        o8.x = f2fp8pk4(a.x, a.y, a.z, a.w);
        o8.y = f2fp8pk4(bb.x, bb.y, bb.z, bb.w);
        o8.z = f2fp8pk4(c.x, c.y, c.z, c.w);
        o8.w = f2fp8pk4(d.x, d.y, d.z, d.w);
        *(uint4*)(x8 + i) = o8;
    }
}

// per-bucket LDS counting sort; int4 reads (CAP region is 16B-aligned + padded)
__global__ __launch_bounds__(256) void bucket_sort_kernel(const int* __restrict__ gCurRel,
                                                          const int* __restrict__ bedges,
                                                          int* __restrict__ csr,
                                                          int2* __restrict__ off2) {
    __shared__ int sdata[256];
    __shared__ int cur[256];
    int b = blockIdx.x, t = threadIdx.x;
    int r0 = b * CAP;
    int n = gCurRel[b];                       // relative cursor = bucket count
    if (n > CAP) n = CAP;
    cur[t] = 0;
    __syncthreads();
    for (int k = t * 4; k < n; k += 1024) {
        int4 v4 = *(const int4*)(bedges + r0 + k);
        int m = n - k;
        atomicAdd(&cur[(unsigned)v4.x >> 24], 1);
        if (m > 1) atomicAdd(&cur[(unsigned)v4.y >> 24], 1);
        if (m > 2) atomicAdd(&cur[(unsigned)v4.z >> 24], 1);
        if (m > 3) atomicAdd(&cur[(unsigned)v4.w >> 24], 1);
    }
    __syncthreads();
    int c = cur[t];
    sdata[t] = c;
    __syncthreads();
    for (int d = 1; d < 256; d <<= 1) {
        int u = (t >= d) ? sdata[t - d] : 0;
        __syncthreads();
        sdata[t] += u;
        __syncthreads();
    }
    int ex = (t == 0) ? 0 : sdata[t - 1];
    off2[(b << BSHIFT) + t] = make_int2(r0 + ex, c);
    cur[t] = ex;
    __syncthreads();
    for (int k = t * 4; k < n; k += 1024) {
        int4 v4 = *(const int4*)(bedges + r0 + k);
        int m = n - k;
        {
            int p = atomicAdd(&cur[(unsigned)v4.x >> 24], 1);
            csr[r0 + p] = v4.x & 0xFFFFFF;
        }
        if (m > 1) {
            int p = atomicAdd(&cur[(unsigned)v4.y >> 24], 1);
            csr[r0 + p] = v4.y & 0xFFFFFF;
        }
        if (m > 2) {
            int p = atomicAdd(&cur[(unsigned)v4.z >> 24], 1);
            csr[r0 + p] = v4.z & 0xFFFFFF;
        }
        if (m > 3) {
            int p = atomicAdd(&cur[(unsigned)v4.w >> 24], 1);
            csr[r0 + p] = v4.w & 0xFFFFFF;
        }
    }
}

// ---------------- fused gather(x8) + MLP1 + BOTH layer-2 pretransforms ----------------
// 32 nodes/block, 8 lanes/node (empirically optimal for 128-B rows). Gather ->
// mtile (LDS). GEMM1: h = relu([mean|x]@W1+b1) -> htile (LDS only).
// Stage 2: g8 = fp8(h@W2_l). Stage 3: f2 = bf16(h@W2_r). h never touches HBM.
#define HSTRIDE 132   // 128-col bf16 rows, +4 pad breaks 256B bank stride
__global__ __launch_bounds__(256) void mfma_mlp_fused_kernel(
        const int2* __restrict__ off2, const int* __restrict__ csr_src,
        const uchar_t* __restrict__ x8,
        const ushort_t* __restrict__ Ax,
        const ushort_t* __restrict__ pack1, const float* __restrict__ bias,
        const ushort_t* __restrict__ pack2l, const ushort_t* __restrict__ pack2r,
        ushort_t* __restrict__ f2, uchar_t* __restrict__ g8) {
    __shared__ ushort_t mtile[32 * HSTRIDE];
    __shared__ ushort_t htile[32 * HSTRIDE];
    long m0b = (long)blockIdx.x * 32;
    // --- prologue: gather 128-dim fp8 mean for this block's 32 rows into LDS ---
    {
        int lane8 = threadIdx.x & 7;          // 16 dims (16 B) per lane
        int local = threadIdx.x >> 3;         // node within block
        long i = m0b + local;                 // exact grid: always < N_NODES
        int2 bd = off2[i];
        const uchar_t* gbase = x8 + lane8 * 16;
        f32x2 acc2[8];
        #pragma unroll
        for (int j = 0; j < 8; ++j) acc2[j] = (f32x2){0.f, 0.f};
        gather_acc_fp8n<7, 1, 8, 1>(gbase, csr_src + bd.x, bd.y, acc2);
        float* pa = (float*)acc2;
        float inv = (bd.y > 0) ? 1.f / (float)bd.y : 0.f;
        uint4 o0, o1;
        o0.x = pack2bf(pa[0] * inv,  pa[1] * inv);
        o0.y = pack2bf(pa[2] * inv,  pa[3] * inv);
        o0.z = pack2bf(pa[4] * inv,  pa[5] * inv);
        o0.w = pack2bf(pa[6] * inv,  pa[7] * inv);
        o1.x = pack2bf(pa[8] * inv,  pa[9] * inv);
        o1.y = pack2bf(pa[10] * inv, pa[11] * inv);
        o1.z = pack2bf(pa[12] * inv, pa[13] * inv);
        o1.w = pack2bf(pa[14] * inv, pa[15] * inv);
        ushort_t* mp = mtile + local * HSTRIDE + lane8 * 16;
        *(uint4*)mp = o0;
        *(uint4*)(mp + 8) = o1;
    }
    __syncthreads();
    // --- GEMM1: h = relu([mean|x]@W1 + b1), 32 rows x 128 cols, K=256 ---
    int lane = threadIdx.x & 63;
    int wave = threadIdx.x >> 6;
    int wr = wave & 1;                        // row group (16 rows)
    int wc = wave >> 1;                       // col group (64 cols)
    int r = lane & 15;
    int quad = lane >> 4;
    int rowl = wr * 16 + r;
    long arow = m0b + rowl;

    bf16x8 areg[8];
    #pragma unroll
    for (int kt = 0; kt < 8; ++kt) {
        int k = (kt & 3) * 32 + quad * 8;
        areg[kt] = (kt < 4)
            ? *(const bf16x8*)(&mtile[rowl * HSTRIDE + k])
            : *(const bf16x8*)(Ax + arow * 128 + k);
    }

    f32x4 acc[4];
    #pragma unroll
    for (int nt = 0; nt < 4; ++nt) acc[nt] = (f32x4){0.f, 0.f, 0.f, 0.f};
    #pragma unroll
    for (int nt = 0; nt < 4; ++nt) {
        int gnt = wc * 4 + nt;
        #pragma unroll
        for (int kt = 0; kt < 8; ++kt) {
            bf16x8 bfrag = *(const bf16x8*)(pack1 + ((long)(gnt * 8 + kt) * 64 + lane) * 8);
            acc[nt] = __builtin_amdgcn_mfma_f32_16x16x32_bf16(areg[kt], bfrag, acc[nt], 0, 0, 0);
        }
    }

    // epilogue: h -> shared LDS tile (row = wr*16+quad*4+q, col = wc*64+nt*16+r)
    #pragma unroll
    for (int nt = 0; nt < 4; ++nt) {
        int col = wc * 64 + nt * 16 + r;
        float bj = bias[col];
        #pragma unroll
        for (int q = 0; q < 4; ++q) {
            float v = fmaxf(acc[nt][q] + bj, 0.f);
            htile[(wr * 16 + quad * 4 + q) * HSTRIDE + col] = f2bf(v);
        }
    }
    __syncthreads();   // htile cols span both col-groups; stages 2/3 read full K
    // --- stage 2: g8 = fp8(h @ W2_l), 32 rows x 64 cols, K=128 ---
    bf16x8 areg2[4];
    #pragma unroll
    for (int kt = 0; kt < 4; ++kt)
        areg2[kt] = *(const bf16x8*)(&htile[rowl * HSTRIDE + kt * 32 + quad * 8]);
    f32x4 gacc[2];
    #pragma unroll
    for (int nt = 0; nt < 2; ++nt) gacc[nt] = (f32x4){0.f, 0.f, 0.f, 0.f};
    #pragma unroll
    for (int nt = 0; nt < 2; ++nt) {
        int gnt = wc * 2 + nt;
        #pragma unroll
        for (int kt = 0; kt < 4; ++kt) {
            bf16x8 bfrag = *(const bf16x8*)(pack2l + ((long)(gnt * 4 + kt) * 64 + lane) * 8);
            gacc[nt] = __builtin_amdgcn_mfma_f32_16x16x32_bf16(areg2[kt], bfrag, gacc[nt], 0, 0, 0);
        }
    }
    #pragma unroll
    for (int nt = 0; nt < 2; ++nt) {
        int col = wc * 32 + nt * 16 + r;
        #pragma unroll
        for (int q = 0; q < 4; ++q) {
            long orow = m0b + wr * 16 + quad * 4 + q;
            g8[orow * 64 + col] = f2fp8_byte(gacc[nt][q]);
        }
    }
    // --- stage 3: f2 = bf16(h @ W2_r), 32 rows x 64 cols, K=128 ---
    f32x4 facc[2];
    #pragma unroll
    for (int nt = 0; nt < 2; ++nt) facc[nt] = (f32x4){0.f, 0.f, 0.f, 0.f};
    #pragma unroll
    for (int nt = 0; nt < 2; ++nt) {
        int gnt = wc * 2 + nt;
        #pragma unroll
        for (int kt = 0; kt < 4; ++kt) {
            bf16x8 bfrag = *(const bf16x8*)(pack2r + ((long)(gnt * 4 + kt) * 64 + lane) * 8);
            facc[nt] = __builtin_amdgcn_mfma_f32_16x16x32_bf16(areg2[kt], bfrag, facc[nt], 0, 0, 0);
        }
    }
    #pragma unroll
    for (int nt = 0; nt < 2; ++nt) {
        int col = wc * 32 + nt * 16 + r;
        #pragma unroll
        for (int q = 0; q < 4; ++q) {
            long orow = m0b + wr * 16 + quad * 4 + q;
            f2[orow * 64 + col] = f2bf(facc[nt][q]);
        }
    }
}

// ---------------- final: pure gather(g8) + out = relu(mean + f2 + b2) ----------------
// 32 nodes/block, 8 lanes/node = 4 dim-slices x 2 edge-parities. Each thread sums
// every other edge; partial sums combined via shfl_xor(4). No LDS, no MFMA.
// f2/b2 loads issued BEFORE the gather so their latency hides under it.
__global__ __launch_bounds__(256) void final_gather_kernel(
        const int2* __restrict__ off2, const int* __restrict__ csr_src,
        const uchar_t* __restrict__ g8,
        const ushort_t* __restrict__ f2, const float* __restrict__ b2,
        float* __restrict__ out) {
    int lane8 = threadIdx.x & 7;
    int d = lane8 & 3;                        // dim slice (16 dims / 16 B)
    int p = lane8 >> 2;                       // edge parity
    int local = threadIdx.x >> 3;
    long i = (long)blockIdx.x * 32 + local;   // exact grid: always < N_NODES
    int2 bd = off2[i];
    int n = bd.y;
    int dim0 = d * 16 + p * 8;
    // issue independent loads early (hide under gather)
    ushort_t fu[8];
    *(uint4*)fu = *(const uint4*)(f2 + i * 64 + dim0);
    float4 bj0 = *(const float4*)(b2 + dim0);
    float4 bj1 = *(const float4*)(b2 + dim0 + 4);
    const uchar_t* base = g8 + d * 16;
    f32x2 acc2[8];
    #pragma unroll
    for (int j = 0; j < 8; ++j) acc2[j] = (f32x2){0.f, 0.f};
    int np = (n + 1 - p) >> 1;                // #edges of this parity
    gather_acc_fp8n<6, 1, 8, 2>(base, csr_src + bd.x + p, np, acc2);
    float* pa = (float*)acc2;
    // combine parities: lane^4 is the partner (same node, same dim slice)
    #pragma unroll
    for (int j = 0; j < 16; ++j) pa[j] += __shfl_xor(pa[j], 4);
    float inv = (n > 0) ? 1.f / (float)n : 0.f;
    float bja[8] = {bj0.x, bj0.y, bj0.z, bj0.w, bj1.x, bj1.y, bj1.z, bj1.w};
    float o[8];
    #pragma unroll
    for (int j = 0; j < 8; ++j) {
        float m = bf2f(f2bf(pa[p * 8 + j] * inv));   // keep bf16-mean rounding
        o[j] = fmaxf(m + bf2f(fu[j]) + bja[j], 0.f);
    }
    *(float4*)(out + i * 64 + dim0)     = make_float4(o[0], o[1], o[2], o[3]);
    *(float4*)(out + i * 64 + dim0 + 4) = make_float4(o[4], o[5], o[6], o[7]);
}

extern "C" void kernel_launch(void* const* d_in, const int* in_sizes, int n_in,
                              void* d_out, int out_size, void* d_ws, size_t ws_size,
                              hipStream_t stream) {
    const float* x    = (const float*)d_in[0];
    const int*   ei   = (const int*)d_in[1];
    const float* W1_l = (const float*)d_in[2];
    const float* W1_r = (const float*)d_in[3];
    const float* b1   = (const float*)d_in[4];
    const float* W2_l = (const float*)d_in[5];
    const float* W2_r = (const float*)d_in[6];
    const float* b2   = (const float*)d_in[7];
    float* out = (float*)d_out;

    const int* src = ei;
    const int* dst = ei + N_EDGES;

    // workspace layout (16B aligned). hb eliminated (h lives only in LDS);
    // f2 [N][64] bf16 carries the layer-2 self term.
    int*  gCur   = (int*)d_ws;                        // 512 (relative cursors)
    int2* off2   = (int2*)(gCur + 512);               // 100608 int2
    int*  bedges = (int*)(off2 + 100608);             // NB*CAP
    int*  csr    = bedges + NB * CAP;                 // NB*CAP
    ushort_t* xb = (ushort_t*)(csr + NB * CAP);       // 25.6 MB row-major [N][128] bf16
    uchar_t*  x8 = (uchar_t*)(xb + (long)N_NODES * 128); // 12.8 MB fp8 [N][128]
    ushort_t* f2 = (ushort_t*)(x8 + (long)N_NODES * 128); // 12.8 MB bf16 [N][64]
    ushort_t* pack1  = f2 + (long)N_NODES * 64;       // 256*128 bf16
    ushort_t* pack2l = pack1 + 256 * 128;             // 128*64
    ushort_t* pack2r = pack2l + 128 * 64;             // 128*64
    uchar_t*  g8     = (uchar_t*)(pack2r + 128 * 64); // 6.4 MB fp8 [N][64]

    // ---- cursor zero-init (graph-capture-safe), then merged prep:
    //      edge scatter || weight packs || x->bf16/fp8, one launch ----
    hipMemsetAsync(gCur, 0, NB * sizeof(int), stream);
    prep_kernel<<<CVT_BASE + CVT_BLOCKS, 256, 0, stream>>>(
        src, dst, gCur, bedges,
        W1_l, W1_r, pack1, W2_l, pack2l, W2_r, pack2r, x, xb, x8);

    // ---- CSR finalize (per-bucket counting sort) ----
    bucket_sort_kernel<<<NB, 256, 0, stream>>>(gCur, bedges, csr, off2);

    // ---- layer 1 + layer-2 pretransforms (fully fused, 32 nodes/block):
    //      mean = gather(x8) in LDS; h = relu([mean|x]@W1+b1) in LDS;
    //      g8 = fp8(h@W2_l); f2 = bf16(h@W2_r) ----
    mfma_mlp_fused_kernel<<<N_NODES / 32, 256, 0, stream>>>(
        off2, csr, x8, xb, pack1, b1, pack2l, pack2r, f2, g8);

    // ---- layer 2: out = relu(gather-mean(g8) + f2 + b2), pure gather ----
    final_gather_kernel<<<N_NODES / 32, 256, 0, stream>>>(
        off2, csr, g8, f2, b2, out);
}